// Round 11
// baseline (220.092 us; speedup 1.0000x reference)
//
#include <hip/hip_runtime.h>

// ResGCNBlock: out = LN(relu(scatter_add(norm * (xW^T+b)[row] -> col))) + x
// N=50000, D=128, E=800000, fp32.
// Round 11: decoupled-lookback scan — k_partial/k_scanp/k_rowptrc merged into
//   one kernel (pipeline 7 -> 5 launches). Everything else = passing round 10.
//   Facts bank: global atomics dead on gfx950 (~26 G ops/s memory-side; r4
//   privatization null, r7 scope-demotion null) -> LDS histograms (r8).
//   __shfl from a lane inactive at the instruction is UNDEFINED (r5/r9 fails);
//   quad k_agg needs wave-uniform trip counts (r10 fix, passed).

#define D 128
#define CHSH 15                      // chunk = 32768 edges per hist block
#define CHUNK (1 << CHSH)
#define NWORD 12500                  // ceil(50000/4) packed-byte LDS words

typedef short bf16x8 __attribute__((ext_vector_type(8)));
typedef float f32x4 __attribute__((ext_vector_type(4)));

__device__ __forceinline__ unsigned short f2bf(float f) {
    unsigned u = __float_as_uint(f);
    return (unsigned short)((u + 0x7fffu + ((u >> 16) & 1u)) >> 16);
}
__device__ __forceinline__ float bf2f_lo(unsigned v) { return __uint_as_float(v << 16); }
__device__ __forceinline__ float bf2f_hi(unsigned v) { return __uint_as_float(v & 0xffff0000u); }

// ---------- fp32 -> bf16 cast (W only) + zero the scan flags ----------
__global__ void k_cast4(const float4* __restrict__ src, ushort4* __restrict__ dst, int n4,
                        unsigned* __restrict__ flags) {
    int i = blockIdx.x * 256 + threadIdx.x;
    if (blockIdx.x == 0) flags[threadIdx.x] = 0u;     // 256 >= 196 scan blocks
    if (i < n4) {
        float4 v = src[i];
        ushort4 o;
        o.x = f2bf(v.x); o.y = f2bf(v.y); o.z = f2bf(v.z); o.w = f2bf(v.w);
        dst[i] = o;
    }
}

// ---------- merged (1024-thr): cnt-hist [0,K) + deg-hist [K,2K) + GEMM rest ----------
__global__ void __launch_bounds__(1024)
k_gemm_hist(const float* __restrict__ x, const unsigned short* __restrict__ wb,
            const float* __restrict__ bias, unsigned short* __restrict__ hb,
            int nrows,
            const int* __restrict__ ei, int E, int n,
            unsigned char* __restrict__ degc, unsigned char* __restrict__ cntc,
            unsigned char* __restrict__ aux, int K) {
    __shared__ unsigned hist[NWORD];
    int bid = blockIdx.x;
    if (bid < 2 * K) {
        bool is_cnt = bid < K;
        int c = is_cnt ? bid : bid - K;
        const int* vs = is_cnt ? (ei + E) : ei;       // dest for cnt, source for deg
        for (int i = threadIdx.x; i < NWORD; i += 1024) hist[i] = 0u;
        __syncthreads();
        int e0 = c << CHSH;
        int e1 = e0 + CHUNK; if (e1 > E) e1 = E;
        if (is_cnt) {
            for (int e = e0 + threadIdx.x; e < e1; e += 1024) {
                int v = vs[e];
                unsigned sh = (v & 3) * 8;
                unsigned old = atomicAdd(&hist[v >> 2], 1u << sh);
                aux[e] = (unsigned char)(old >> sh);  // rank within (chunk, dest)
            }
        } else {
            for (int e = e0 + threadIdx.x; e < e1; e += 1024) {
                int v = vs[e];
                atomicAdd(&hist[v >> 2], 1u << ((v & 3) * 8));
            }
        }
        __syncthreads();
        unsigned* dst = (unsigned*)((is_cnt ? cntc : degc) + (size_t)c * n);
        for (int i = threadIdx.x; i < NWORD; i += 1024) dst[i] = hist[i];
    } else {
        // ---- GEMM role: 16 waves, 256 rows per block ----
        int wid = threadIdx.x >> 6, lane = threadIdx.x & 63;
        int m0 = (bid - 2 * K) * 256 + wid * 16;
        if (m0 >= nrows) return;
        int lo16 = lane & 15, quad = lane >> 4;
        const float* arow = x + (size_t)(m0 + lo16) * D + quad * 8;
        bf16x8 a[4];
        #pragma unroll
        for (int kt = 0; kt < 4; kt++) {
            float4 p = *(const float4*)(arow + kt * 32);
            float4 q = *(const float4*)(arow + kt * 32 + 4);
            bf16x8 av;
            av[0] = (short)f2bf(p.x); av[1] = (short)f2bf(p.y);
            av[2] = (short)f2bf(p.z); av[3] = (short)f2bf(p.w);
            av[4] = (short)f2bf(q.x); av[5] = (short)f2bf(q.y);
            av[6] = (short)f2bf(q.z); av[7] = (short)f2bf(q.w);
            a[kt] = av;
        }
        #pragma unroll
        for (int nt = 0; nt < 8; nt++) {
            int n0 = nt * 16;
            const unsigned short* brow = wb + (size_t)(n0 + lo16) * D + quad * 8;
            float bj = bias[n0 + lo16];
            f32x4 acc = {bj, bj, bj, bj};
            #pragma unroll
            for (int kt = 0; kt < 4; kt++) {
                bf16x8 b = *(const bf16x8*)(brow + kt * 32);
                acc = __builtin_amdgcn_mfma_f32_16x16x32_bf16(a[kt], b, acc, 0, 0, 0);
            }
            #pragma unroll
            for (int r = 0; r < 4; r++) {
                int gr = m0 + quad * 4 + r;
                hb[(size_t)gr * D + n0 + lo16] = f2bf(acc[r]);
            }
        }
    }
}

// ---------- single-kernel scan: dis + rowptr + rowptrc via decoupled lookback ----------
// Safe: all 196 blocks co-resident (<= 256 CUs); lookback only waits on
// lower-indexed blocks (dispatched earlier). Flag word: [31:30] state
// (0 empty / 1 aggregate / 2 inclusive-prefix), [29:0] value (E < 2^20).
__global__ void k_scan(const unsigned char* __restrict__ degc,
                       const unsigned char* __restrict__ cntc,
                       float* __restrict__ dis,
                       int* __restrict__ rowptr, int* __restrict__ rowptrc,
                       unsigned* __restrict__ flags, int n, int E, int K) {
    __shared__ unsigned s[256];
    __shared__ unsigned sbase;
    int t = threadIdx.x;
    int bid = blockIdx.x;
    int i = bid * 256 + t;
    unsigned tot = 0;
    if (i < n) {
        unsigned d = 0;
        for (int c = 0; c < K; c++) d += degc[(size_t)c * n + i];
        dis[i] = rsqrtf((float)d + 1.0f);          // +1 = self loop
        for (int c = 0; c < K; c++) tot += cntc[(size_t)c * n + i];
    }
    s[t] = tot;                                    // inclusive block scan
    __syncthreads();
    #pragma unroll
    for (int d = 1; d < 256; d <<= 1) {
        unsigned u = (t >= d) ? s[t - d] : 0u;
        __syncthreads();
        s[t] += u;
        __syncthreads();
    }
    unsigned incl = s[t];
    unsigned aggregate = s[255];
    if (t == 0) {
        __hip_atomic_store(&flags[bid], (1u << 30) | aggregate,
                           __ATOMIC_RELEASE, __HIP_MEMORY_SCOPE_AGENT);
        unsigned ex = 0;
        for (int p = bid - 1; p >= 0; p--) {
            unsigned f;
            do {
                f = __hip_atomic_load(&flags[p], __ATOMIC_ACQUIRE,
                                      __HIP_MEMORY_SCOPE_AGENT);
            } while ((f >> 30) == 0u);
            ex += f & 0x3FFFFFFFu;
            if ((f >> 30) == 2u) break;            // found a full prefix
        }
        __hip_atomic_store(&flags[bid], (2u << 30) | (ex + aggregate),
                           __ATOMIC_RELEASE, __HIP_MEMORY_SCOPE_AGENT);
        sbase = ex;
    }
    __syncthreads();
    unsigned base = sbase;
    if (i < n) {
        int rb = (int)(base + incl - tot);         // exclusive global prefix
        rowptr[i] = rb;
        unsigned run = 0;
        for (int c = 0; c < K; c++) {
            rowptrc[(size_t)c * n + i] = rb + (int)run;
            run += cntc[(size_t)c * n + i];
        }
    }
    if (i == n - 1) rowptr[n] = E;
}

// ---------- atomic-free bucket fill using (copy = e>>CHSH, rank = aux[e]) ----------
__global__ void k_fill(const int* __restrict__ ei, int E, int n,
                       const int* __restrict__ rowptrc, const unsigned char* __restrict__ aux,
                       int* __restrict__ srcs) {
    int e = blockIdx.x * 256 + threadIdx.x;
    if (e < E) {
        int r = ei[e];
        int v = ei[E + e];
        int c = e >> CHSH;
        srcs[rowptrc[(size_t)c * n + v] + (int)aux[e]] = r;
    }
}

// ---------- fused gather-aggregate + self-loop + relu + LN + residual ----------
// one wave per dest row; quad q (16 lanes) handles edges j==q (mod 4); lane t
// owns cols 8t..8t+7 (16B uint4 of bf16 per edge). Uniform trip count; all
// shuffles full-wave (ds_bpermute from inactive lanes is UNDEFINED on gfx950).
__global__ void k_agg(const float* __restrict__ x, const unsigned short* __restrict__ hb,
                      const float* __restrict__ dis,
                      const int* __restrict__ rowptr, const int* __restrict__ srcs,
                      const float* __restrict__ gamma, const float* __restrict__ beta,
                      float* __restrict__ out, int n) {
    int wid = threadIdx.x >> 6, lane = threadIdx.x & 63;
    int row = blockIdx.x * 4 + wid;
    if (row >= n) return;
    int q = lane >> 4, t = lane & 15;
    float dc = dis[row];
    float acc[8];
    #pragma unroll
    for (int i = 0; i < 8; i++) acc[i] = 0.0f;
    if (q == 0) {                                     // self-loop: dis^2 * h[row]
        uint4 u = ((const uint4*)(hb + (size_t)row * D))[t];
        float sn = dc * dc;
        acc[0] = sn * bf2f_lo(u.x); acc[1] = sn * bf2f_hi(u.x);
        acc[2] = sn * bf2f_lo(u.y); acc[3] = sn * bf2f_hi(u.y);
        acc[4] = sn * bf2f_lo(u.z); acc[5] = sn * bf2f_hi(u.z);
        acc[6] = sn * bf2f_lo(u.w); acc[7] = sn * bf2f_hi(u.w);
    }
    int s0 = rowptr[row];
    int len = rowptr[row + 1] - s0;
    for (int base = 0; base < len; base += 64) {
        int idx = base + lane;
        int sv = (idx < len) ? srcs[s0 + idx] : 0;    // pad: row 0
        float dv = (idx < len) ? dis[sv] : 0.0f;      // pad: weight 0 (self-masks)
        int m = len - base; if (m > 64) m = 64;
        int kmax = (m + 3) >> 2;                      // wave-uniform trip count
        int j = q;
        int r = __shfl(sv, j, 64);                    // full-wave shuffle: defined
        float nm = dc * __shfl(dv, j, 64);            // 0 if j >= m
        uint4 u = ((const uint4*)(hb + (size_t)r * D))[t];
        for (int k = 1; k < kmax; k++) {
            int jn = j + 4;                           // jn <= 63 (kmax <= 16)
            int rn = __shfl(sv, jn, 64);              // prefetch next edge
            float nmn = dc * __shfl(dv, jn, 64);
            uint4 un = ((const uint4*)(hb + (size_t)rn * D))[t];
            acc[0] += nm * bf2f_lo(u.x); acc[1] += nm * bf2f_hi(u.x);
            acc[2] += nm * bf2f_lo(u.y); acc[3] += nm * bf2f_hi(u.y);
            acc[4] += nm * bf2f_lo(u.z); acc[5] += nm * bf2f_hi(u.z);
            acc[6] += nm * bf2f_lo(u.w); acc[7] += nm * bf2f_hi(u.w);
            u = un; nm = nmn; j = jn;
        }
        acc[0] += nm * bf2f_lo(u.x); acc[1] += nm * bf2f_hi(u.x);
        acc[2] += nm * bf2f_lo(u.y); acc[3] += nm * bf2f_hi(u.y);
        acc[4] += nm * bf2f_lo(u.z); acc[5] += nm * bf2f_hi(u.z);
        acc[6] += nm * bf2f_lo(u.w); acc[7] += nm * bf2f_hi(u.w);
    }
    // combine the 4 quads' partials (lanes t, t+16, t+32, t+48), then relu
    #pragma unroll
    for (int i = 0; i < 8; i++) {
        acc[i] += __shfl_xor(acc[i], 16, 64);
        acc[i] += __shfl_xor(acc[i], 32, 64);
        acc[i] = acc[i] > 0.0f ? acc[i] : 0.0f;
    }
    // LN over 128 cols: per-lane partial over its 8 cols, reduce across t
    float s1r = 0.0f, s2r = 0.0f;
    #pragma unroll
    for (int i = 0; i < 8; i++) { s1r += acc[i]; s2r += acc[i] * acc[i]; }
    #pragma unroll
    for (int mm = 8; mm >= 1; mm >>= 1) {
        s1r += __shfl_xor(s1r, mm, 64);
        s2r += __shfl_xor(s2r, mm, 64);
    }
    float mean = s1r * (1.0f / 128.0f);
    float var  = s2r * (1.0f / 128.0f) - mean * mean;  // population var (jnp.var)
    float rstd = rsqrtf(var + 1e-5f);
    if (q == 0) {                                      // 16 lanes store the row
        const float4* gr = (const float4*)gamma;
        const float4* br = (const float4*)beta;
        const float4* xr = (const float4*)(x + (size_t)row * D);
        float4* orow = (float4*)(out + (size_t)row * D);
        #pragma unroll
        for (int hf = 0; hf < 2; hf++) {
            float4 g = gr[2 * t + hf], b = br[2 * t + hf], xx = xr[2 * t + hf];
            float4 o;
            o.x = (acc[4 * hf + 0] - mean) * rstd * g.x + b.x + xx.x;
            o.y = (acc[4 * hf + 1] - mean) * rstd * g.y + b.y + xx.y;
            o.z = (acc[4 * hf + 2] - mean) * rstd * g.z + b.z + xx.z;
            o.w = (acc[4 * hf + 3] - mean) * rstd * g.w + b.w + xx.w;
            orow[2 * t + hf] = o;
        }
    }
}

extern "C" void kernel_launch(void* const* d_in, const int* in_sizes, int n_in,
                              void* d_out, int out_size, void* d_ws, size_t ws_size,
                              hipStream_t stream) {
    const float* x     = (const float*)d_in[0];
    const int*   ei    = (const int*)d_in[1];   // [2, E]
    const float* W     = (const float*)d_in[2];
    const float* bias  = (const float*)d_in[3];
    const float* gamma = (const float*)d_in[4];
    const float* beta  = (const float*)d_in[5];
    int N = in_sizes[0] / D;
    int E = in_sizes[1] / 2;
    int nb  = (N + 255) / 256;                   // 196 scan blocks (<=256)
    int nbE = (E + 255) / 256;                   // 3125
    int K   = (E + CHUNK - 1) >> CHSH;           // 25 chunks / copies
    int gemm_blocks = (N + 255) / 256;           // 196 (256 rows per 1024-thr block)

    char* ws = (char*)d_ws;
    size_t off = 0;
    unsigned short* hb  = (unsigned short*)(ws + off); off += (size_t)N * D * 2;       // 12.8 MB
    unsigned short* wbf = (unsigned short*)(ws + off); off += (size_t)D * D * 2;       // 32 KB
    unsigned char* degc = (unsigned char*)(ws + off);  off += (size_t)K * N;           // 1.25 MB
    unsigned char* cntc = (unsigned char*)(ws + off);  off += (size_t)K * N;           // 1.25 MB
    float*    dis       = (float*)(ws + off);          off += (size_t)N * 4;
    int*      rowptr    = (int*)(ws + off);            off += (size_t)(N + 1) * 4;
    int*      rowptrc   = (int*)(ws + off);            off += (size_t)K * N * 4;       // 5 MB
    unsigned* flags     = (unsigned*)(ws + off);       off += 256 * 4;
    unsigned char* aux  = (unsigned char*)(ws + off);  off += (size_t)E;               // 0.8 MB
    int*      srcs      = (int*)(ws + off);            off += (size_t)E * 4;           // 3.2 MB
    float*    out       = (float*)d_out;

    k_cast4<<<(D * D / 4 + 255) / 256, 256, 0, stream>>>((const float4*)W, (ushort4*)wbf,
                                                         D * D / 4, flags);
    k_gemm_hist<<<2 * K + gemm_blocks, 1024, 0, stream>>>(x, wbf, bias, hb, N,
                                                          ei, E, N, degc, cntc, aux, K);
    k_scan<<<nb, 256, 0, stream>>>(degc, cntc, dis, rowptr, rowptrc, flags, N, E, K);
    k_fill<<<nbE, 256, 0, stream>>>(ei, E, N, rowptrc, aux, srcs);
    k_agg<<<(N + 3) / 4, 256, 0, stream>>>(x, hb, dis, rowptr, srcs, gamma, beta, out, N);
}

// Round 12
// 185.244 us; speedup vs baseline: 1.1881x; 1.1881x over previous
//
#include <hip/hip_runtime.h>

// ResGCNBlock: out = LN(relu(scatter_add(norm * (xW^T+b)[row] -> col))) + x
// N=50000, D=128, E=800000, fp32.
// Round 12: wave-parallel decoupled lookback (r11's serial walk was 60 µs of
//   pure flag-latency; CUB-style 64-wide polling + RELAXED loads — the flag
//   word is the only cross-block data, so no acquire ordering needed).
//   Facts bank: global atomics dead on gfx950 (~26 G ops/s memory-side; r4
//   privatization null, r7 scope-demotion null) -> LDS histograms (r8).
//   __shfl from a lane inactive at the instruction is UNDEFINED (r5/r9);
//   all shuffles/ballots below execute wave-uniformly (r10 fix, passed).

#define D 128
#define CHSH 15                      // chunk = 32768 edges per hist block
#define CHUNK (1 << CHSH)
#define NWORD 12500                  // ceil(50000/4) packed-byte LDS words

typedef short bf16x8 __attribute__((ext_vector_type(8)));
typedef float f32x4 __attribute__((ext_vector_type(4)));

__device__ __forceinline__ unsigned short f2bf(float f) {
    unsigned u = __float_as_uint(f);
    return (unsigned short)((u + 0x7fffu + ((u >> 16) & 1u)) >> 16);
}
__device__ __forceinline__ float bf2f_lo(unsigned v) { return __uint_as_float(v << 16); }
__device__ __forceinline__ float bf2f_hi(unsigned v) { return __uint_as_float(v & 0xffff0000u); }

// ---------- fp32 -> bf16 cast (W only) + zero the scan flags ----------
__global__ void k_cast4(const float4* __restrict__ src, ushort4* __restrict__ dst, int n4,
                        unsigned* __restrict__ flags) {
    int i = blockIdx.x * 256 + threadIdx.x;
    if (blockIdx.x == 0) flags[threadIdx.x] = 0u;     // 256 >= 196 scan blocks
    if (i < n4) {
        float4 v = src[i];
        ushort4 o;
        o.x = f2bf(v.x); o.y = f2bf(v.y); o.z = f2bf(v.z); o.w = f2bf(v.w);
        dst[i] = o;
    }
}

// ---------- merged (1024-thr): cnt-hist [0,K) + deg-hist [K,2K) + GEMM rest ----------
__global__ void __launch_bounds__(1024)
k_gemm_hist(const float* __restrict__ x, const unsigned short* __restrict__ wb,
            const float* __restrict__ bias, unsigned short* __restrict__ hb,
            int nrows,
            const int* __restrict__ ei, int E, int n,
            unsigned char* __restrict__ degc, unsigned char* __restrict__ cntc,
            unsigned char* __restrict__ aux, int K) {
    __shared__ unsigned hist[NWORD];
    int bid = blockIdx.x;
    if (bid < 2 * K) {
        bool is_cnt = bid < K;
        int c = is_cnt ? bid : bid - K;
        const int* vs = is_cnt ? (ei + E) : ei;       // dest for cnt, source for deg
        for (int i = threadIdx.x; i < NWORD; i += 1024) hist[i] = 0u;
        __syncthreads();
        int e0 = c << CHSH;
        int e1 = e0 + CHUNK; if (e1 > E) e1 = E;
        if (is_cnt) {
            for (int e = e0 + threadIdx.x; e < e1; e += 1024) {
                int v = vs[e];
                unsigned sh = (v & 3) * 8;
                unsigned old = atomicAdd(&hist[v >> 2], 1u << sh);
                aux[e] = (unsigned char)(old >> sh);  // rank within (chunk, dest)
            }
        } else {
            for (int e = e0 + threadIdx.x; e < e1; e += 1024) {
                int v = vs[e];
                atomicAdd(&hist[v >> 2], 1u << ((v & 3) * 8));
            }
        }
        __syncthreads();
        unsigned* dst = (unsigned*)((is_cnt ? cntc : degc) + (size_t)c * n);
        for (int i = threadIdx.x; i < NWORD; i += 1024) dst[i] = hist[i];
    } else {
        // ---- GEMM role: 16 waves, 256 rows per block ----
        int wid = threadIdx.x >> 6, lane = threadIdx.x & 63;
        int m0 = (bid - 2 * K) * 256 + wid * 16;
        if (m0 >= nrows) return;
        int lo16 = lane & 15, quad = lane >> 4;
        const float* arow = x + (size_t)(m0 + lo16) * D + quad * 8;
        bf16x8 a[4];
        #pragma unroll
        for (int kt = 0; kt < 4; kt++) {
            float4 p = *(const float4*)(arow + kt * 32);
            float4 q = *(const float4*)(arow + kt * 32 + 4);
            bf16x8 av;
            av[0] = (short)f2bf(p.x); av[1] = (short)f2bf(p.y);
            av[2] = (short)f2bf(p.z); av[3] = (short)f2bf(p.w);
            av[4] = (short)f2bf(q.x); av[5] = (short)f2bf(q.y);
            av[6] = (short)f2bf(q.z); av[7] = (short)f2bf(q.w);
            a[kt] = av;
        }
        #pragma unroll
        for (int nt = 0; nt < 8; nt++) {
            int n0 = nt * 16;
            const unsigned short* brow = wb + (size_t)(n0 + lo16) * D + quad * 8;
            float bj = bias[n0 + lo16];
            f32x4 acc = {bj, bj, bj, bj};
            #pragma unroll
            for (int kt = 0; kt < 4; kt++) {
                bf16x8 b = *(const bf16x8*)(brow + kt * 32);
                acc = __builtin_amdgcn_mfma_f32_16x16x32_bf16(a[kt], b, acc, 0, 0, 0);
            }
            #pragma unroll
            for (int r = 0; r < 4; r++) {
                int gr = m0 + quad * 4 + r;
                hb[(size_t)gr * D + n0 + lo16] = f2bf(acc[r]);
            }
        }
    }
}

// ---------- single-kernel scan: dis + rowptr + rowptrc, wave-parallel lookback ----------
// All 196 blocks co-resident; lookback waits only on lower-indexed blocks.
// Flag word: [31:30] state (0 empty / 1 aggregate / 2 inclusive), [29:0] value.
// Lane l of wave 0 polls flags[p0-l] (RELAXED — the flag word is the only
// cross-block data); __ballot picks nearest state-2; <=4 serial rounds.
__global__ void k_scan(const unsigned char* __restrict__ degc,
                       const unsigned char* __restrict__ cntc,
                       float* __restrict__ dis,
                       int* __restrict__ rowptr, int* __restrict__ rowptrc,
                       unsigned* __restrict__ flags, int n, int E, int K) {
    __shared__ unsigned s[256];
    __shared__ unsigned sbase;
    int t = threadIdx.x;
    int bid = blockIdx.x;
    int i = bid * 256 + t;
    unsigned tot = 0;
    if (i < n) {
        unsigned d = 0;
        for (int c = 0; c < K; c++) d += degc[(size_t)c * n + i];
        dis[i] = rsqrtf((float)d + 1.0f);          // +1 = self loop
        for (int c = 0; c < K; c++) tot += cntc[(size_t)c * n + i];
    }
    s[t] = tot;                                    // inclusive block scan
    __syncthreads();
    #pragma unroll
    for (int d = 1; d < 256; d <<= 1) {
        unsigned u = (t >= d) ? s[t - d] : 0u;
        __syncthreads();
        s[t] += u;
        __syncthreads();
    }
    unsigned incl = s[t];
    unsigned aggregate = s[255];
    if (t < 64) {                                  // wave 0: cooperative lookback
        if (t == 0)
            __hip_atomic_store(&flags[bid], (1u << 30) | aggregate,
                               __ATOMIC_RELEASE, __HIP_MEMORY_SCOPE_AGENT);
        unsigned ex = 0;
        int p0 = bid - 1;
        while (p0 >= 0) {                          // wave-uniform loop
            int p = p0 - t;                        // lane t polls predecessor p
            unsigned f = 0;
            if (p >= 0) {
                do {
                    f = __hip_atomic_load(&flags[p], __ATOMIC_RELAXED,
                                          __HIP_MEMORY_SCOPE_AGENT);
                } while ((f >> 30) == 0u);
            }
            // nearest state-2 = lowest lane with state 2 (block 0 is always 2)
            unsigned long long ball = __ballot(p >= 0 && (f >> 30) == 2u);
            int first = ball ? (__ffsll((unsigned long long)ball) - 1) : 64;
            unsigned contrib = (p >= 0 && t <= first) ? (f & 0x3FFFFFFFu) : 0u;
            #pragma unroll
            for (int mm = 32; mm >= 1; mm >>= 1)
                contrib += __shfl_xor(contrib, mm, 64);
            ex += contrib;
            if (first < 64) break;
            p0 -= 64;
        }
        if (t == 0) {
            __hip_atomic_store(&flags[bid], (2u << 30) | (ex + aggregate),
                               __ATOMIC_RELEASE, __HIP_MEMORY_SCOPE_AGENT);
            sbase = ex;
        }
    }
    __syncthreads();
    unsigned base = sbase;
    if (i < n) {
        int rb = (int)(base + incl - tot);         // exclusive global prefix
        rowptr[i] = rb;
        unsigned run = 0;
        for (int c = 0; c < K; c++) {
            rowptrc[(size_t)c * n + i] = rb + (int)run;
            run += cntc[(size_t)c * n + i];
        }
    }
    if (i == n - 1) rowptr[n] = E;
}

// ---------- atomic-free bucket fill using (copy = e>>CHSH, rank = aux[e]) ----------
__global__ void k_fill(const int* __restrict__ ei, int E, int n,
                       const int* __restrict__ rowptrc, const unsigned char* __restrict__ aux,
                       int* __restrict__ srcs) {
    int e = blockIdx.x * 256 + threadIdx.x;
    if (e < E) {
        int r = ei[e];
        int v = ei[E + e];
        int c = e >> CHSH;
        srcs[rowptrc[(size_t)c * n + v] + (int)aux[e]] = r;
    }
}

// ---------- fused gather-aggregate + self-loop + relu + LN + residual ----------
// one wave per dest row; quad q (16 lanes) handles edges j==q (mod 4); lane t
// owns cols 8t..8t+7 (16B uint4 of bf16 per edge). Uniform trip count; all
// shuffles full-wave (ds_bpermute from inactive lanes is UNDEFINED on gfx950).
__global__ void k_agg(const float* __restrict__ x, const unsigned short* __restrict__ hb,
                      const float* __restrict__ dis,
                      const int* __restrict__ rowptr, const int* __restrict__ srcs,
                      const float* __restrict__ gamma, const float* __restrict__ beta,
                      float* __restrict__ out, int n) {
    int wid = threadIdx.x >> 6, lane = threadIdx.x & 63;
    int row = blockIdx.x * 4 + wid;
    if (row >= n) return;
    int q = lane >> 4, t = lane & 15;
    float dc = dis[row];
    float acc[8];
    #pragma unroll
    for (int i = 0; i < 8; i++) acc[i] = 0.0f;
    if (q == 0) {                                     // self-loop: dis^2 * h[row]
        uint4 u = ((const uint4*)(hb + (size_t)row * D))[t];
        float sn = dc * dc;
        acc[0] = sn * bf2f_lo(u.x); acc[1] = sn * bf2f_hi(u.x);
        acc[2] = sn * bf2f_lo(u.y); acc[3] = sn * bf2f_hi(u.y);
        acc[4] = sn * bf2f_lo(u.z); acc[5] = sn * bf2f_hi(u.z);
        acc[6] = sn * bf2f_lo(u.w); acc[7] = sn * bf2f_hi(u.w);
    }
    int s0 = rowptr[row];
    int len = rowptr[row + 1] - s0;
    for (int base = 0; base < len; base += 64) {
        int idx = base + lane;
        int sv = (idx < len) ? srcs[s0 + idx] : 0;    // pad: row 0
        float dv = (idx < len) ? dis[sv] : 0.0f;      // pad: weight 0 (self-masks)
        int m = len - base; if (m > 64) m = 64;
        int kmax = (m + 3) >> 2;                      // wave-uniform trip count
        int j = q;
        int r = __shfl(sv, j, 64);                    // full-wave shuffle: defined
        float nm = dc * __shfl(dv, j, 64);            // 0 if j >= m
        uint4 u = ((const uint4*)(hb + (size_t)r * D))[t];
        for (int k = 1; k < kmax; k++) {
            int jn = j + 4;                           // jn <= 63 (kmax <= 16)
            int rn = __shfl(sv, jn, 64);              // prefetch next edge
            float nmn = dc * __shfl(dv, jn, 64);
            uint4 un = ((const uint4*)(hb + (size_t)rn * D))[t];
            acc[0] += nm * bf2f_lo(u.x); acc[1] += nm * bf2f_hi(u.x);
            acc[2] += nm * bf2f_lo(u.y); acc[3] += nm * bf2f_hi(u.y);
            acc[4] += nm * bf2f_lo(u.z); acc[5] += nm * bf2f_hi(u.z);
            acc[6] += nm * bf2f_lo(u.w); acc[7] += nm * bf2f_hi(u.w);
            u = un; nm = nmn; j = jn;
        }
        acc[0] += nm * bf2f_lo(u.x); acc[1] += nm * bf2f_hi(u.x);
        acc[2] += nm * bf2f_lo(u.y); acc[3] += nm * bf2f_hi(u.y);
        acc[4] += nm * bf2f_lo(u.z); acc[5] += nm * bf2f_hi(u.z);
        acc[6] += nm * bf2f_lo(u.w); acc[7] += nm * bf2f_hi(u.w);
    }
    // combine the 4 quads' partials (lanes t, t+16, t+32, t+48), then relu
    #pragma unroll
    for (int i = 0; i < 8; i++) {
        acc[i] += __shfl_xor(acc[i], 16, 64);
        acc[i] += __shfl_xor(acc[i], 32, 64);
        acc[i] = acc[i] > 0.0f ? acc[i] : 0.0f;
    }
    // LN over 128 cols: per-lane partial over its 8 cols, reduce across t
    float s1r = 0.0f, s2r = 0.0f;
    #pragma unroll
    for (int i = 0; i < 8; i++) { s1r += acc[i]; s2r += acc[i] * acc[i]; }
    #pragma unroll
    for (int mm = 8; mm >= 1; mm >>= 1) {
        s1r += __shfl_xor(s1r, mm, 64);
        s2r += __shfl_xor(s2r, mm, 64);
    }
    float mean = s1r * (1.0f / 128.0f);
    float var  = s2r * (1.0f / 128.0f) - mean * mean;  // population var (jnp.var)
    float rstd = rsqrtf(var + 1e-5f);
    if (q == 0) {                                      // 16 lanes store the row
        const float4* gr = (const float4*)gamma;
        const float4* br = (const float4*)beta;
        const float4* xr = (const float4*)(x + (size_t)row * D);
        float4* orow = (float4*)(out + (size_t)row * D);
        #pragma unroll
        for (int hf = 0; hf < 2; hf++) {
            float4 g = gr[2 * t + hf], b = br[2 * t + hf], xx = xr[2 * t + hf];
            float4 o;
            o.x = (acc[4 * hf + 0] - mean) * rstd * g.x + b.x + xx.x;
            o.y = (acc[4 * hf + 1] - mean) * rstd * g.y + b.y + xx.y;
            o.z = (acc[4 * hf + 2] - mean) * rstd * g.z + b.z + xx.z;
            o.w = (acc[4 * hf + 3] - mean) * rstd * g.w + b.w + xx.w;
            orow[2 * t + hf] = o;
        }
    }
}

extern "C" void kernel_launch(void* const* d_in, const int* in_sizes, int n_in,
                              void* d_out, int out_size, void* d_ws, size_t ws_size,
                              hipStream_t stream) {
    const float* x     = (const float*)d_in[0];
    const int*   ei    = (const int*)d_in[1];   // [2, E]
    const float* W     = (const float*)d_in[2];
    const float* bias  = (const float*)d_in[3];
    const float* gamma = (const float*)d_in[4];
    const float* beta  = (const float*)d_in[5];
    int N = in_sizes[0] / D;
    int E = in_sizes[1] / 2;
    int nb  = (N + 255) / 256;                   // 196 scan blocks (<=256)
    int nbE = (E + 255) / 256;                   // 3125
    int K   = (E + CHUNK - 1) >> CHSH;           // 25 chunks / copies
    int gemm_blocks = (N + 255) / 256;           // 196 (256 rows per 1024-thr block)

    char* ws = (char*)d_ws;
    size_t off = 0;
    unsigned short* hb  = (unsigned short*)(ws + off); off += (size_t)N * D * 2;       // 12.8 MB
    unsigned short* wbf = (unsigned short*)(ws + off); off += (size_t)D * D * 2;       // 32 KB
    unsigned char* degc = (unsigned char*)(ws + off);  off += (size_t)K * N;           // 1.25 MB
    unsigned char* cntc = (unsigned char*)(ws + off);  off += (size_t)K * N;           // 1.25 MB
    float*    dis       = (float*)(ws + off);          off += (size_t)N * 4;
    int*      rowptr    = (int*)(ws + off);            off += (size_t)(N + 1) * 4;
    int*      rowptrc   = (int*)(ws + off);            off += (size_t)K * N * 4;       // 5 MB
    unsigned* flags     = (unsigned*)(ws + off);       off += 256 * 4;
    unsigned char* aux  = (unsigned char*)(ws + off);  off += (size_t)E;               // 0.8 MB
    int*      srcs      = (int*)(ws + off);            off += (size_t)E * 4;           // 3.2 MB
    float*    out       = (float*)d_out;

    k_cast4<<<(D * D / 4 + 255) / 256, 256, 0, stream>>>((const float4*)W, (ushort4*)wbf,
                                                         D * D / 4, flags);
    k_gemm_hist<<<2 * K + gemm_blocks, 1024, 0, stream>>>(x, wbf, bias, hb, N,
                                                          ei, E, N, degc, cntc, aux, K);
    k_scan<<<nb, 256, 0, stream>>>(degc, cntc, dis, rowptr, rowptrc, flags, N, E, K);
    k_fill<<<nbE, 256, 0, stream>>>(ei, E, N, rowptrc, aux, srcs);
    k_agg<<<(N + 3) / 4, 256, 0, stream>>>(x, hb, dis, rowptr, srcs, gamma, beta, out, N);
}